// Round 13
// baseline (289.445 us; speedup 1.0000x reference)
//
#include <hip/hip_runtime.h>
#include <float.h>

constexpr int DIN = 128;
constexpr int D1  = 256;
constexpr int HH  = 4;
constexpr int CC  = 64;

typedef _Float16 f16;
typedef __attribute__((ext_vector_type(2))) _Float16 f16x2;
typedef __attribute__((ext_vector_type(4))) _Float16 f16x4;
typedef __attribute__((ext_vector_type(8))) _Float16 f16x8;
typedef __attribute__((ext_vector_type(2))) float f32x2;
typedef __attribute__((ext_vector_type(4))) float f32x4;
typedef unsigned char u8;

#if __has_builtin(__builtin_amdgcn_cvt_pk_f32_fp8) && __has_builtin(__builtin_amdgcn_cvt_pk_fp8_f32)
#define HAS_CVT_FP8 1
#else
#define HAS_CVT_FP8 0
#include <hip/hip_fp8.h>
#endif

__device__ __forceinline__ u8 f2fp8(float f) {
#if HAS_CVT_FP8
    return (u8)(__builtin_amdgcn_cvt_pk_fp8_f32(f, f, 0, false) & 0xff);
#else
    __hip_fp8_e4m3 t(f);
    return (u8)t.__x;
#endif
}

// decode 4 fp8 (one dword) and fma with scalar weight into acc
__device__ __forceinline__ void fp8fma(unsigned w, float a, float4& acc) {
#if HAS_CVT_FP8
    f32x2 lo = __builtin_amdgcn_cvt_pk_f32_fp8((int)w, false);
    f32x2 hi = __builtin_amdgcn_cvt_pk_f32_fp8((int)w, true);
    acc.x = fmaf(lo[0], a, acc.x);
    acc.y = fmaf(lo[1], a, acc.y);
    acc.z = fmaf(hi[0], a, acc.z);
    acc.w = fmaf(hi[1], a, acc.w);
#else
    __hip_fp8_e4m3 b0, b1, b2, b3;
    b0.__x = (w) & 0xff; b1.__x = (w >> 8) & 0xff;
    b2.__x = (w >> 16) & 0xff; b3.__x = (w >> 24) & 0xff;
    acc.x = fmaf((float)b0, a, acc.x);
    acc.y = fmaf((float)b1, a, acc.y);
    acc.z = fmaf((float)b2, a, acc.z);
    acc.w = fmaf((float)b3, a, acc.w);
#endif
}

__device__ __forceinline__ float wave_sum(float v) {
    #pragma unroll
    for (int off = 32; off > 0; off >>= 1) v += __shfl_down(v, off, 64);
    return v;
}

// ---------------- fused W prep: pack (MFMA order) + make_v ----------------
__global__ __launch_bounds__(256) void prep_w_kernel(
        const float* __restrict__ Wsrc1, const float* __restrict__ Wlin1,
        const float* __restrict__ Wsrc2, const float* __restrict__ Wlin2,
        const float* __restrict__ Wdst1, const float* __restrict__ Wdst2,
        const float* __restrict__ atts1, const float* __restrict__ attd1,
        const float* __restrict__ atts2, const float* __restrict__ attd2,
        f16* __restrict__ WpS1, f16* __restrict__ WpL1,
        f16* __restrict__ WpS2, f16* __restrict__ WpL2,
        float* __restrict__ Vs1, float* __restrict__ Vd1,
        float* __restrict__ Vs2, float* __restrict__ Vd2, int nb_pack) {
    if ((int)blockIdx.x < nb_pack) {
        int idx = blockIdx.x * 256 + threadIdx.x;
        const float *Wa, *Wb;
        f16 *Wpa, *Wpb;
        if (idx < DIN * D1) { Wa = Wsrc1; Wb = Wlin1; Wpa = WpS1; Wpb = WpL1; }
        else {
            idx -= DIN * D1;
            if (idx >= D1 * D1) return;
            Wa = Wsrc2; Wb = Wlin2; Wpa = WpS2; Wpb = WpL2;
        }
        int j    = idx & 7;
        int lane = (idx >> 3) & 63;
        int t    = idx >> 9;          // kt*16 + ct
        int ct   = t & 15, kt = t >> 4;
        int k    = kt * 32 + (lane >> 4) * 8 + j;
        int col  = ct * 16 + (lane & 15);
        size_t widx = (size_t)k * D1 + col;
        Wpa[idx] = (f16)Wa[widx];
        Wpb[idx] = (f16)Wb[widx];
    } else {
        int b2  = blockIdx.x - nb_pack;
        int mat = b2 & 1;
        int kb  = b2 >> 1;
        int h = threadIdx.x >> 6, lane = threadIdx.x & 63;
        const float *W, *att;
        float* V;
        int k;
        if (kb < DIN) {
            k = kb;
            W = mat ? Wdst1 : Wsrc1; att = mat ? attd1 : atts1; V = mat ? Vd1 : Vs1;
        } else {
            k = kb - DIN;
            W = mat ? Wdst2 : Wsrc2; att = mat ? attd2 : atts2; V = mat ? Vd2 : Vs2;
        }
        float v = W[(size_t)k * D1 + h * CC + lane] * att[h * CC + lane];
        v = wave_sum(v);
        if (lane == 0) V[k * HH + h] = v;
    }
}

// ---------------- fused fp32->f16 convert + layer-1 scores ----------------
__global__ __launch_bounds__(256) void cvt_scores_kernel(
        const float* __restrict__ X, const float* __restrict__ Vs,
        const float* __restrict__ Vd, f16* __restrict__ X16,
        float* __restrict__ a_s, float* __restrict__ a_d, int n) {
    constexpr int K = DIN, C = 32, SH = 5;
    __shared__ float4 VsL[K + 4];
    __shared__ float4 VdL[K + 4];
    for (int k = threadIdx.x; k < K; k += 256) {
        int ki = k + (k >> SH);
        VsL[ki] = reinterpret_cast<const float4*>(Vs)[k];
        VdL[ki] = reinterpret_cast<const float4*>(Vd)[k];
    }
    __syncthreads();

    const int lane  = threadIdx.x & 63;
    const int wid   = threadIdx.x >> 6;
    const int node  = blockIdx.x * 64 + wid * 16 + (lane >> 2);
    const int chunk = lane & 3;
    const int nodec = min(node, n - 1);
    const float* xp = X + (size_t)nodec * K + chunk * C;

    float xv[C];
    #pragma unroll
    for (int b = 0; b < C / 4; ++b) {
        float4 v = reinterpret_cast<const float4*>(xp)[b];
        xv[b * 4 + 0] = v.x; xv[b * 4 + 1] = v.y;
        xv[b * 4 + 2] = v.z; xv[b * 4 + 3] = v.w;
    }
    if (node < n) {
        f16* op = X16 + (size_t)node * K + chunk * C;
        #pragma unroll
        for (int b = 0; b < C / 8; ++b) {
            f16x8 o;
            #pragma unroll
            for (int t = 0; t < 8; ++t) o[t] = (f16)xv[b * 8 + t];
            reinterpret_cast<f16x8*>(op)[b] = o;
        }
    }

    float ps0 = 0.f, ps1 = 0.f, ps2 = 0.f, ps3 = 0.f;
    float pd0 = 0.f, pd1 = 0.f, pd2 = 0.f, pd3 = 0.f;
    #pragma unroll
    for (int t = 0; t < C; ++t) {
        int k  = chunk * C + t;
        int ki = k + (k >> SH);
        float xf = xv[t];
        float4 vs = VsL[ki];
        float4 vd = VdL[ki];
        ps0 = fmaf(xf, vs.x, ps0); ps1 = fmaf(xf, vs.y, ps1);
        ps2 = fmaf(xf, vs.z, ps2); ps3 = fmaf(xf, vs.w, ps3);
        pd0 = fmaf(xf, vd.x, pd0); pd1 = fmaf(xf, vd.y, pd1);
        pd2 = fmaf(xf, vd.z, pd2); pd3 = fmaf(xf, vd.w, pd3);
    }
    #pragma unroll
    for (int off = 1; off <= 2; off <<= 1) {
        ps0 += __shfl_xor(ps0, off, 64); ps1 += __shfl_xor(ps1, off, 64);
        ps2 += __shfl_xor(ps2, off, 64); ps3 += __shfl_xor(ps3, off, 64);
        pd0 += __shfl_xor(pd0, off, 64); pd1 += __shfl_xor(pd1, off, 64);
        pd2 += __shfl_xor(pd2, off, 64); pd3 += __shfl_xor(pd3, off, 64);
    }
    if (node < n) {
        float psv = chunk == 0 ? ps0 : chunk == 1 ? ps1 : chunk == 2 ? ps2 : ps3;
        float pdv = chunk == 0 ? pd0 : chunk == 1 ? pd1 : chunk == 2 ? pd2 : pd3;
        a_s[node * 4 + chunk] = psv;
        a_d[node * 4 + chunk] = pdv;
    }
}

// ---------------- CSR build ----------------
__global__ __launch_bounds__(256) void deg_kernel(
        const int* __restrict__ dst, int* __restrict__ deg, int ne) {
    int e = blockIdx.x * 256 + threadIdx.x;
    if (e < ne) atomicAdd(deg + dst[e], 1);
}

__global__ __launch_bounds__(1024) void scan_phase1(
        const int* __restrict__ deg, int* __restrict__ partial,
        int* __restrict__ blocksum, int n) {
    __shared__ int tmp[1024];
    const int tid = threadIdx.x;
    int i = blockIdx.x * 1024 + tid;
    int v = (i < n) ? deg[i] : 0;
    tmp[tid] = v;
    __syncthreads();
    #pragma unroll
    for (int off = 1; off < 1024; off <<= 1) {
        int t = (tid >= off) ? tmp[tid - off] : 0;
        __syncthreads();
        tmp[tid] += t;
        __syncthreads();
    }
    if (i < n) partial[i] = tmp[tid];
    if (tid == 1023) blocksum[blockIdx.x] = tmp[1023];
}

// phase3 computes its own blocksum prefix (nb_scan <= 64)
__global__ __launch_bounds__(1024) void scan_phase3(
        const int* __restrict__ partial, const int* __restrict__ blocksum,
        const int* __restrict__ deg, int* __restrict__ rowptr,
        int* __restrict__ degcur, int n) {
    __shared__ int add_s;
    if (threadIdx.x < 64) {
        int lane = threadIdx.x;
        int v = (lane < (int)blockIdx.x) ? blocksum[lane] : 0;
        #pragma unroll
        for (int off = 32; off > 0; off >>= 1) v += __shfl_down(v, off, 64);
        if (lane == 0) add_s = v;
    }
    __syncthreads();
    const int add = add_s;
    int i = blockIdx.x * 1024 + threadIdx.x;
    if (i >= n) return;
    int incl = partial[i] + add;
    rowptr[i + 1] = incl;
    degcur[i] = incl - deg[i];
    if (i == 0) rowptr[0] = 0;
}

__global__ __launch_bounds__(256) void fill_kernel(
        const int* __restrict__ src, const int* __restrict__ dst,
        int* __restrict__ cursor, int* __restrict__ srcs_csr, int ne) {
    int e = blockIdx.x * 256 + threadIdx.x;
    if (e >= ne) return;
    int pos = atomicAdd(cursor + dst[e], 1);
    srcs_csr[pos] = src[e];
}

// ---------------- dual MFMA GEMM (f16 in, fp8 O1 / f16 O2), 64-row blocks --
template <int K>
__global__ __launch_bounds__(256) void gemm_dual_mfma(
        const f16* __restrict__ A, const f16* __restrict__ Wp1,
        const f16* __restrict__ Wp2, const float* __restrict__ bias1,
        const float* __restrict__ bias2, u8* __restrict__ O1,
        f16* __restrict__ O2, int n) {
    constexpr int KT = K / 32;
    const int lane = threadIdx.x & 63;
    const int w    = threadIdx.x >> 6;
    const int row0 = blockIdx.x * 64;
    const int col0 = w * 64;

    f32x4 acc1[4][4], acc2[4][4];
    const f32x4 zero = {0.f, 0.f, 0.f, 0.f};
    #pragma unroll
    for (int i = 0; i < 4; ++i)
        #pragma unroll
        for (int j = 0; j < 4; ++j) { acc1[i][j] = zero; acc2[i][j] = zero; }

    const f16* Arow[4];
    #pragma unroll
    for (int rf = 0; rf < 4; ++rf) {
        int ar = min(row0 + rf * 16 + (lane & 15), n - 1);
        Arow[rf] = A + (size_t)ar * K + (lane >> 4) * 8;
    }
    const f16* Wb1 = Wp1 + ((size_t)(w * 4) * 64 + lane) * 8;
    const f16* Wb2 = Wp2 + ((size_t)(w * 4) * 64 + lane) * 8;

    #pragma unroll
    for (int kt = 0; kt < KT; ++kt) {
        f16x8 a[4];
        #pragma unroll
        for (int rf = 0; rf < 4; ++rf)
            a[rf] = *reinterpret_cast<const f16x8*>(Arow[rf] + kt * 32);
        #pragma unroll
        for (int cf = 0; cf < 4; ++cf) {
            f16x8 b1v = *reinterpret_cast<const f16x8*>(Wb1 + (size_t)(kt * 16 + cf) * 512);
            f16x8 b2v = *reinterpret_cast<const f16x8*>(Wb2 + (size_t)(kt * 16 + cf) * 512);
            #pragma unroll
            for (int rf = 0; rf < 4; ++rf) {
                acc1[rf][cf] = __builtin_amdgcn_mfma_f32_16x16x32_f16(a[rf], b1v, acc1[rf][cf], 0, 0, 0);
                acc2[rf][cf] = __builtin_amdgcn_mfma_f32_16x16x32_f16(a[rf], b2v, acc2[rf][cf], 0, 0, 0);
            }
        }
    }

    #pragma unroll
    for (int cf = 0; cf < 4; ++cf) {
        const int col = col0 + cf * 16 + (lane & 15);
        const float bsum = bias1[col] + bias2[col];
        #pragma unroll
        for (int rf = 0; rf < 4; ++rf) {
            #pragma unroll
            for (int r = 0; r < 4; ++r) {
                const int row = row0 + rf * 16 + (lane >> 4) * 4 + r;
                if (row < n) {
                    O1[(size_t)row * D1 + col] = f2fp8(acc1[rf][cf][r]);
                    O2[(size_t)row * D1 + col] = (f16)(acc2[rf][cf][r] + bsum);
                }
            }
        }
    }
}

// ---------------- fused per-node GAT gather (fp8 xs, 8B loads) ----------------
// Alpha phase: head-parallel, 16-edge chunks (lane = h*16+j -> 1 exp/lane).
// Inner loop: 2 edges/iteration-slot via lane-pair split: pair = lane>>5 picks
// the edge, ch32 = lane&31 picks an 8-channel group (one uint2 load).
// End: pair-combine (xor 32) + redistribute to the 4-ch/lane layout the
// epilogues expect. Softmax without max-subtraction (shift-invariant).
#define ALDS_STRIDE 66

__device__ __forceinline__ float4 gat_node_acc(
        const int* __restrict__ srcs, const float* __restrict__ a_s,
        const u8* __restrict__ xs, f16* __restrict__ alds,
        const float* __restrict__ a_d_row, int base, int deg, int lane) {
    const int h    = lane >> 4;
    const int j    = lane & 15;
    const int pair = lane >> 5;
    const int ch32 = lane & 31;
    const f16* arow_i = alds + (ch32 >> 3) * ALDS_STRIDE;
    const float adv = a_d_row[h];
    float den = 0.f;
    float4 accLo = {0.f, 0.f, 0.f, 0.f};
    float4 accHi = {0.f, 0.f, 0.f, 0.f};

    for (int c0 = 0; c0 < deg; c0 += 16) {
        const int cnt = min(16, deg - c0);
        const int idx = c0 + j;
        const bool valid = idx < deg;
        const int sl = srcs[base + min(idx, deg - 1)];
        {
            float e = a_s[(size_t)sl * 4 + h] + adv;
            e = e > 0.f ? e : 0.2f * e;
            float a = valid ? __expf(e) : 0.f;
            den += a;
            alds[h * ALDS_STRIDE + j] = (f16)a;
        }
        asm volatile("s_waitcnt lgkmcnt(0)" ::: "memory");

        const int sv = sl;   // lanes 0..15 hold this chunk's srcs
        for (int i = 0; i < cnt; i += 4) {
            int sA = __shfl(sv, i + pair, 64);
            int sB = __shfl(sv, i + 2 + pair, 64);
            float aA = (float)arow_i[i + pair];
            float aB = (float)arow_i[i + 2 + pair];
            uint2 xA = *reinterpret_cast<const uint2*>(xs + (size_t)sA * D1 + ch32 * 8);
            uint2 xB = *reinterpret_cast<const uint2*>(xs + (size_t)sB * D1 + ch32 * 8);
            fp8fma(xA.x, aA, accLo);
            fp8fma(xA.y, aA, accHi);
            fp8fma(xB.x, aB, accLo);
            fp8fma(xB.y, aB, accHi);
        }
    }

    // combine pair halves (symmetric across lane^32)
    accLo.x += __shfl_xor(accLo.x, 32, 64); accLo.y += __shfl_xor(accLo.y, 32, 64);
    accLo.z += __shfl_xor(accLo.z, 32, 64); accLo.w += __shfl_xor(accLo.w, 32, 64);
    accHi.x += __shfl_xor(accHi.x, 32, 64); accHi.y += __shfl_xor(accHi.y, 32, 64);
    accHi.z += __shfl_xor(accHi.z, 32, 64); accHi.w += __shfl_xor(accHi.w, 32, 64);

    // redistribute 8ch/lane -> 4ch/lane: lane wants channels lane*4..+3,
    // held by lane>>1 in accLo (lane even) or accHi (lane odd)
    const int srcl = lane >> 1;
    float l0 = __shfl(accLo.x, srcl, 64), l1 = __shfl(accLo.y, srcl, 64);
    float l2 = __shfl(accLo.z, srcl, 64), l3 = __shfl(accLo.w, srcl, 64);
    float h0 = __shfl(accHi.x, srcl, 64), h1 = __shfl(accHi.y, srcl, 64);
    float h2 = __shfl(accHi.z, srcl, 64), h3 = __shfl(accHi.w, srcl, 64);
    const bool hi = (lane & 1) != 0;
    float4 acc;
    acc.x = hi ? h0 : l0; acc.y = hi ? h1 : l1;
    acc.z = hi ? h2 : l2; acc.w = hi ? h3 : l3;

    // den reduce within 16-lane head group; lane's head (lane>>4) matches
    // its post-redistribution channels (lane*4/64 == lane>>4)
    #pragma unroll
    for (int off = 1; off < 16; off <<= 1)
        den += __shfl_xor(den, off, 64);
    const float invd = 1.f / (den + 1e-16f);
    acc.x *= invd; acc.y *= invd; acc.z *= invd; acc.w *= invd;
    return acc;
}

// layer-1: h = relu(LN(gather + skip)) -> f16, plus layer-2 scores epilogue
__global__ __launch_bounds__(256) void gat_gather_ln_kernel(
        const int* __restrict__ rowptr, const int* __restrict__ srcs,
        const float* __restrict__ a_s1, const float* __restrict__ a_d1,
        const u8* __restrict__ xs, const f16* __restrict__ skip,
        const float* __restrict__ gamma, const float* __restrict__ beta,
        const float* __restrict__ Vs2, const float* __restrict__ Vd2,
        f16* __restrict__ hout, float* __restrict__ a_s2,
        float* __restrict__ a_d2, int n) {
    __shared__ f16 alpha_lds[4][4 * ALDS_STRIDE];
    const int wid = threadIdx.x >> 6, lane = threadIdx.x & 63;
    const int d = blockIdx.x * 4 + wid;
    if (d >= n) return;
    const int base = rowptr[d];
    const int deg  = rowptr[d + 1] - base;

    float4 acc = {0.f, 0.f, 0.f, 0.f};
    if (deg > 0)
        acc = gat_node_acc(srcs, a_s1, xs, alpha_lds[wid],
                           a_d1 + (size_t)d * 4, base, deg, lane);

    f16x4 sk = *reinterpret_cast<const f16x4*>(skip + (size_t)d * D1 + lane * 4);
    float4 v;
    v.x = acc.x + (float)sk[0];
    v.y = acc.y + (float)sk[1];
    v.z = acc.z + (float)sk[2];
    v.w = acc.w + (float)sk[3];

    float s  = v.x + v.y + v.z + v.w;
    float sq = v.x * v.x + v.y * v.y + v.z * v.z + v.w * v.w;
    #pragma unroll
    for (int off = 32; off > 0; off >>= 1) {
        s  += __shfl_down(s, off, 64);
        sq += __shfl_down(sq, off, 64);
    }
    s  = __shfl(s, 0, 64);
    sq = __shfl(sq, 0, 64);
    float mu  = s * (1.f / 256.f);
    float var = sq * (1.f / 256.f) - mu * mu;
    float rstd = rsqrtf(var + 1e-5f);
    float4 g = *reinterpret_cast<const float4*>(gamma + lane * 4);
    float4 b = *reinterpret_cast<const float4*>(beta + lane * 4);
    f16x4 o;
    o[0] = (f16)fmaxf((v.x - mu) * rstd * g.x + b.x, 0.f);
    o[1] = (f16)fmaxf((v.y - mu) * rstd * g.y + b.y, 0.f);
    o[2] = (f16)fmaxf((v.z - mu) * rstd * g.z + b.z, 0.f);
    o[3] = (f16)fmaxf((v.w - mu) * rstd * g.w + b.w, 0.f);
    *reinterpret_cast<f16x4*>(hout + (size_t)d * D1 + lane * 4) = o;

    // ---- layer-2 scores epilogue (reduce-scatter, 10 shfl) ----
    float of0 = (float)o[0], of1 = (float)o[1], of2 = (float)o[2], of3 = (float)o[3];
    const float4* V4s = reinterpret_cast<const float4*>(Vs2);
    const float4* V4d = reinterpret_cast<const float4*>(Vd2);
    float4 r0 = V4s[lane * 4 + 0], r1 = V4s[lane * 4 + 1];
    float4 r2 = V4s[lane * 4 + 2], r3 = V4s[lane * 4 + 3];
    float v0 = of0 * r0.x + of1 * r1.x + of2 * r2.x + of3 * r3.x;
    float v1 = of0 * r0.y + of1 * r1.y + of2 * r2.y + of3 * r3.y;
    float v2 = of0 * r0.z + of1 * r1.z + of2 * r2.z + of3 * r3.z;
    float v3 = of0 * r0.w + of1 * r1.w + of2 * r2.w + of3 * r3.w;
    r0 = V4d[lane * 4 + 0]; r1 = V4d[lane * 4 + 1];
    r2 = V4d[lane * 4 + 2]; r3 = V4d[lane * 4 + 3];
    float v4 = of0 * r0.x + of1 * r1.x + of2 * r2.x + of3 * r3.x;
    float v5 = of0 * r0.y + of1 * r1.y + of2 * r2.y + of3 * r3.y;
    float v6 = of0 * r0.z + of1 * r1.z + of2 * r2.z + of3 * r3.z;
    float v7 = of0 * r0.w + of1 * r1.w + of2 * r2.w + of3 * r3.w;

    const bool b0 = (lane & 1) != 0;
    float w0 = (b0 ? v1 : v0) + __shfl_xor(b0 ? v0 : v1, 1, 64);
    float w1 = (b0 ? v3 : v2) + __shfl_xor(b0 ? v2 : v3, 1, 64);
    float w2 = (b0 ? v5 : v4) + __shfl_xor(b0 ? v4 : v5, 1, 64);
    float w3 = (b0 ? v7 : v6) + __shfl_xor(b0 ? v6 : v7, 1, 64);
    const bool b1 = (lane & 2) != 0;
    float u0 = (b1 ? w1 : w0) + __shfl_xor(b1 ? w0 : w1, 2, 64);
    float u1 = (b1 ? w3 : w2) + __shfl_xor(b1 ? w2 : w3, 2, 64);
    const bool b2f = (lane & 4) != 0;
    float z = (b2f ? u1 : u0) + __shfl_xor(b2f ? u0 : u1, 4, 64);
    z += __shfl_xor(z, 8, 64);
    z += __shfl_xor(z, 16, 64);
    z += __shfl_xor(z, 32, 64);
    // lane l (l<8) now holds total of value index l: 0-3 -> a_s2, 4-7 -> a_d2
    if (lane < 8) {
        float* outp = (lane < 4) ? (a_s2 + (size_t)d * 4 + lane)
                                 : (a_d2 + (size_t)d * 4 + (lane - 4));
        *outp = z;
    }
}

// layer-2: out = gather + skip2 (write-once fp32, no RMW)
__global__ __launch_bounds__(256) void gat_gather_out_kernel(
        const int* __restrict__ rowptr, const int* __restrict__ srcs,
        const float* __restrict__ a_s, const float* __restrict__ a_d,
        const u8* __restrict__ xs, const f16* __restrict__ skip2,
        float* __restrict__ out, int n) {
    __shared__ f16 alpha_lds[4][4 * ALDS_STRIDE];
    const int wid = threadIdx.x >> 6, lane = threadIdx.x & 63;
    const int d = blockIdx.x * 4 + wid;
    if (d >= n) return;
    const int base = rowptr[d];
    const int deg  = rowptr[d + 1] - base;
    float4 acc = {0.f, 0.f, 0.f, 0.f};
    if (deg > 0)
        acc = gat_node_acc(srcs, a_s, xs, alpha_lds[wid],
                           a_d + (size_t)d * 4, base, deg, lane);
    f16x4 sk = *reinterpret_cast<const f16x4*>(skip2 + (size_t)d * D1 + lane * 4);
    float4 ov;
    ov.x = acc.x + (float)sk[0];
    ov.y = acc.y + (float)sk[1];
    ov.z = acc.z + (float)sk[2];
    ov.w = acc.w + (float)sk[3];
    *reinterpret_cast<float4*>(out + (size_t)d * D1 + lane * 4) = ov;
}

extern "C" void kernel_launch(void* const* d_in, const int* in_sizes, int n_in,
                              void* d_out, int out_size, void* d_ws, size_t ws_size,
                              hipStream_t stream) {
    const float* x     = (const float*)d_in[0];
    const int*   ei    = (const int*)d_in[1];
    const float* Wsrc1 = (const float*)d_in[2];
    const float* Wdst1 = (const float*)d_in[3];
    const float* atts1 = (const float*)d_in[4];
    const float* attd1 = (const float*)d_in[5];
    const float* b1    = (const float*)d_in[6];
    const float* Wlin1 = (const float*)d_in[7];
    const float* blin1 = (const float*)d_in[8];
    const float* gamma = (const float*)d_in[9];
    const float* beta  = (const float*)d_in[10];
    const float* Wsrc2 = (const float*)d_in[11];
    const float* Wdst2 = (const float*)d_in[12];
    const float* atts2 = (const float*)d_in[13];
    const float* attd2 = (const float*)d_in[14];
    const float* b2    = (const float*)d_in[15];
    const float* Wlin2 = (const float*)d_in[16];
    const float* blin2 = (const float*)d_in[17];

    const int n  = in_sizes[0] / DIN;   // 50000
    const int ne = in_sizes[1] / 2;     // 800000
    const int* src = ei;
    const int* dst = ei + ne;

    char* w8 = (char*)d_ws;
    size_t off = 0;
    auto alloc = [&](size_t bytes) -> void* {
        void* p = w8 + off;
        off += (bytes + 255) & ~(size_t)255;
        return p;
    };
    f16*  h16    = (f16*)alloc((size_t)n * D1 * 2);
    f16*  x16    = h16;   // union: x16 dead before gather_ln writes h16
    u8*   xs8    = (u8*)alloc((size_t)n * D1);
    f16*  skip1  = (f16*)alloc((size_t)n * D1 * 2);   // reused as skip2
    float* a_s1  = (float*)alloc((size_t)n * HH * 4);
    float* a_d1  = (float*)alloc((size_t)n * HH * 4);
    float* a_s2  = (float*)alloc((size_t)n * HH * 4);
    float* a_d2  = (float*)alloc((size_t)n * HH * 4);
    float* Vs1   = (float*)alloc((size_t)D1 * HH * 4);
    float* Vd1   = (float*)alloc((size_t)D1 * HH * 4);
    float* Vs2   = (float*)alloc((size_t)D1 * HH * 4);
    float* Vd2   = (float*)alloc((size_t)D1 * HH * 4);
    int* rowptr   = (int*)alloc(((size_t)n + 1) * 4);
    int* degbuf   = (int*)alloc((size_t)n * 4);
    int* degcur   = (int*)alloc((size_t)n * 4);
    int* partial  = (int*)alloc((size_t)n * 4);
    int* blocksum = (int*)alloc(1024 * 4);
    int* srcs_csr = (int*)alloc((size_t)ne * 4);
    f16* WpS1  = (f16*)alloc((size_t)DIN * D1 * 2);
    f16* WpL1  = (f16*)alloc((size_t)DIN * D1 * 2);
    f16* WpS2  = (f16*)alloc((size_t)D1 * D1 * 2);
    f16* WpL2  = (f16*)alloc((size_t)D1 * D1 * 2);

    float* out = (float*)d_out;

    const int nb_node4  = (n + 3) / 4;
    const int nb_node64 = (n + 63) / 64;
    const int nb_e      = (ne + 255) / 256;
    const int nb_gemm   = (n + 63) / 64;
    const int nb_scan   = (n + 1023) / 1024;
    const int nb_pack   = (DIN * D1 + D1 * D1 + 255) / 256;

    // ---------------- prep ----------------
    (void)hipMemsetAsync(degbuf, 0, (size_t)n * 4, stream);
    deg_kernel<<<nb_e, 256, 0, stream>>>(dst, degbuf, ne);
    scan_phase1<<<nb_scan, 1024, 0, stream>>>(degbuf, partial, blocksum, n);
    scan_phase3<<<nb_scan, 1024, 0, stream>>>(partial, blocksum, degbuf, rowptr, degcur, n);
    fill_kernel<<<nb_e, 256, 0, stream>>>(src, dst, degcur, srcs_csr, ne);
    prep_w_kernel<<<nb_pack + 2 * (DIN + D1), 256, 0, stream>>>(
        Wsrc1, Wlin1, Wsrc2, Wlin2, Wdst1, Wdst2,
        atts1, attd1, atts2, attd2,
        WpS1, WpL1, WpS2, WpL2, Vs1, Vd1, Vs2, Vd2, nb_pack);

    // ---------------- layer 1 ----------------
    cvt_scores_kernel<<<nb_node64, 256, 0, stream>>>(x, Vs1, Vd1, x16, a_s1, a_d1, n);
    gemm_dual_mfma<DIN><<<nb_gemm, 256, 0, stream>>>(x16, WpS1, WpL1, b1, blin1, xs8, skip1, n);
    gat_gather_ln_kernel<<<nb_node4, 256, 0, stream>>>(rowptr, srcs_csr, a_s1, a_d1, xs8,
                                                       skip1, gamma, beta, Vs2, Vd2,
                                                       h16, a_s2, a_d2, n);

    // ---------------- layer 2 ----------------
    gemm_dual_mfma<D1><<<nb_gemm, 256, 0, stream>>>(h16, WpS2, WpL2, b2, blin2, xs8, skip1, n);
    gat_gather_out_kernel<<<nb_node4, 256, 0, stream>>>(rowptr, srcs_csr, a_s2, a_d2,
                                                        xs8, skip1, out, n);
}

// Round 14
// 280.060 us; speedup vs baseline: 1.0335x; 1.0335x over previous
//
#include <hip/hip_runtime.h>
#include <float.h>

constexpr int DIN = 128;
constexpr int D1  = 256;
constexpr int HH  = 4;
constexpr int CC  = 64;

typedef _Float16 f16;
typedef __attribute__((ext_vector_type(2))) _Float16 f16x2;
typedef __attribute__((ext_vector_type(4))) _Float16 f16x4;
typedef __attribute__((ext_vector_type(8))) _Float16 f16x8;
typedef __attribute__((ext_vector_type(2))) float f32x2;
typedef __attribute__((ext_vector_type(4))) float f32x4;
typedef unsigned char u8;

#if __has_builtin(__builtin_amdgcn_cvt_pk_f32_fp8) && __has_builtin(__builtin_amdgcn_cvt_pk_fp8_f32)
#define HAS_CVT_FP8 1
#else
#define HAS_CVT_FP8 0
#include <hip/hip_fp8.h>
#endif

__device__ __forceinline__ u8 f2fp8(float f) {
#if HAS_CVT_FP8
    return (u8)(__builtin_amdgcn_cvt_pk_fp8_f32(f, f, 0, false) & 0xff);
#else
    __hip_fp8_e4m3 t(f);
    return (u8)t.__x;
#endif
}

// decode 4 fp8 (one dword) and fma with scalar weight into acc
__device__ __forceinline__ void fp8fma(unsigned w, float a, float4& acc) {
#if HAS_CVT_FP8
    f32x2 lo = __builtin_amdgcn_cvt_pk_f32_fp8((int)w, false);
    f32x2 hi = __builtin_amdgcn_cvt_pk_f32_fp8((int)w, true);
    acc.x = fmaf(lo[0], a, acc.x);
    acc.y = fmaf(lo[1], a, acc.y);
    acc.z = fmaf(hi[0], a, acc.z);
    acc.w = fmaf(hi[1], a, acc.w);
#else
    __hip_fp8_e4m3 b0, b1, b2, b3;
    b0.__x = (w) & 0xff; b1.__x = (w >> 8) & 0xff;
    b2.__x = (w >> 16) & 0xff; b3.__x = (w >> 24) & 0xff;
    acc.x = fmaf((float)b0, a, acc.x);
    acc.y = fmaf((float)b1, a, acc.y);
    acc.z = fmaf((float)b2, a, acc.z);
    acc.w = fmaf((float)b3, a, acc.w);
#endif
}

__device__ __forceinline__ float wave_sum(float v) {
    #pragma unroll
    for (int off = 32; off > 0; off >>= 1) v += __shfl_down(v, off, 64);
    return v;
}

// ---------------- fused W prep: pack (MFMA order) + make_v ----------------
__global__ __launch_bounds__(256) void prep_w_kernel(
        const float* __restrict__ Wsrc1, const float* __restrict__ Wlin1,
        const float* __restrict__ Wsrc2, const float* __restrict__ Wlin2,
        const float* __restrict__ Wdst1, const float* __restrict__ Wdst2,
        const float* __restrict__ atts1, const float* __restrict__ attd1,
        const float* __restrict__ atts2, const float* __restrict__ attd2,
        f16* __restrict__ WpS1, f16* __restrict__ WpL1,
        f16* __restrict__ WpS2, f16* __restrict__ WpL2,
        float* __restrict__ Vs1, float* __restrict__ Vd1,
        float* __restrict__ Vs2, float* __restrict__ Vd2, int nb_pack) {
    if ((int)blockIdx.x < nb_pack) {
        int idx = blockIdx.x * 256 + threadIdx.x;
        const float *Wa, *Wb;
        f16 *Wpa, *Wpb;
        if (idx < DIN * D1) { Wa = Wsrc1; Wb = Wlin1; Wpa = WpS1; Wpb = WpL1; }
        else {
            idx -= DIN * D1;
            if (idx >= D1 * D1) return;
            Wa = Wsrc2; Wb = Wlin2; Wpa = WpS2; Wpb = WpL2;
        }
        int j    = idx & 7;
        int lane = (idx >> 3) & 63;
        int t    = idx >> 9;          // kt*16 + ct
        int ct   = t & 15, kt = t >> 4;
        int k    = kt * 32 + (lane >> 4) * 8 + j;
        int col  = ct * 16 + (lane & 15);
        size_t widx = (size_t)k * D1 + col;
        Wpa[idx] = (f16)Wa[widx];
        Wpb[idx] = (f16)Wb[widx];
    } else {
        int b2  = blockIdx.x - nb_pack;
        int mat = b2 & 1;
        int kb  = b2 >> 1;
        int h = threadIdx.x >> 6, lane = threadIdx.x & 63;
        const float *W, *att;
        float* V;
        int k;
        if (kb < DIN) {
            k = kb;
            W = mat ? Wdst1 : Wsrc1; att = mat ? attd1 : atts1; V = mat ? Vd1 : Vs1;
        } else {
            k = kb - DIN;
            W = mat ? Wdst2 : Wsrc2; att = mat ? attd2 : atts2; V = mat ? Vd2 : Vs2;
        }
        float v = W[(size_t)k * D1 + h * CC + lane] * att[h * CC + lane];
        v = wave_sum(v);
        if (lane == 0) V[k * HH + h] = v;
    }
}

// ---------------- fused fp32->f16 convert + layer-1 scores ----------------
__global__ __launch_bounds__(256) void cvt_scores_kernel(
        const float* __restrict__ X, const float* __restrict__ Vs,
        const float* __restrict__ Vd, f16* __restrict__ X16,
        float* __restrict__ a_s, float* __restrict__ a_d, int n) {
    constexpr int K = DIN, C = 32, SH = 5;
    __shared__ float4 VsL[K + 4];
    __shared__ float4 VdL[K + 4];
    for (int k = threadIdx.x; k < K; k += 256) {
        int ki = k + (k >> SH);
        VsL[ki] = reinterpret_cast<const float4*>(Vs)[k];
        VdL[ki] = reinterpret_cast<const float4*>(Vd)[k];
    }
    __syncthreads();

    const int lane  = threadIdx.x & 63;
    const int wid   = threadIdx.x >> 6;
    const int node  = blockIdx.x * 64 + wid * 16 + (lane >> 2);
    const int chunk = lane & 3;
    const int nodec = min(node, n - 1);
    const float* xp = X + (size_t)nodec * K + chunk * C;

    float xv[C];
    #pragma unroll
    for (int b = 0; b < C / 4; ++b) {
        float4 v = reinterpret_cast<const float4*>(xp)[b];
        xv[b * 4 + 0] = v.x; xv[b * 4 + 1] = v.y;
        xv[b * 4 + 2] = v.z; xv[b * 4 + 3] = v.w;
    }
    if (node < n) {
        f16* op = X16 + (size_t)node * K + chunk * C;
        #pragma unroll
        for (int b = 0; b < C / 8; ++b) {
            f16x8 o;
            #pragma unroll
            for (int t = 0; t < 8; ++t) o[t] = (f16)xv[b * 8 + t];
            reinterpret_cast<f16x8*>(op)[b] = o;
        }
    }

    float ps0 = 0.f, ps1 = 0.f, ps2 = 0.f, ps3 = 0.f;
    float pd0 = 0.f, pd1 = 0.f, pd2 = 0.f, pd3 = 0.f;
    #pragma unroll
    for (int t = 0; t < C; ++t) {
        int k  = chunk * C + t;
        int ki = k + (k >> SH);
        float xf = xv[t];
        float4 vs = VsL[ki];
        float4 vd = VdL[ki];
        ps0 = fmaf(xf, vs.x, ps0); ps1 = fmaf(xf, vs.y, ps1);
        ps2 = fmaf(xf, vs.z, ps2); ps3 = fmaf(xf, vs.w, ps3);
        pd0 = fmaf(xf, vd.x, pd0); pd1 = fmaf(xf, vd.y, pd1);
        pd2 = fmaf(xf, vd.z, pd2); pd3 = fmaf(xf, vd.w, pd3);
    }
    #pragma unroll
    for (int off = 1; off <= 2; off <<= 1) {
        ps0 += __shfl_xor(ps0, off, 64); ps1 += __shfl_xor(ps1, off, 64);
        ps2 += __shfl_xor(ps2, off, 64); ps3 += __shfl_xor(ps3, off, 64);
        pd0 += __shfl_xor(pd0, off, 64); pd1 += __shfl_xor(pd1, off, 64);
        pd2 += __shfl_xor(pd2, off, 64); pd3 += __shfl_xor(pd3, off, 64);
    }
    if (node < n) {
        float psv = chunk == 0 ? ps0 : chunk == 1 ? ps1 : chunk == 2 ? ps2 : ps3;
        float pdv = chunk == 0 ? pd0 : chunk == 1 ? pd1 : chunk == 2 ? pd2 : pd3;
        a_s[node * 4 + chunk] = psv;
        a_d[node * 4 + chunk] = pdv;
    }
}

// ---------------- CSR build ----------------
__global__ __launch_bounds__(256) void deg_kernel(
        const int* __restrict__ dst, int* __restrict__ deg, int ne) {
    int e = blockIdx.x * 256 + threadIdx.x;
    if (e < ne) atomicAdd(deg + dst[e], 1);
}

__global__ __launch_bounds__(1024) void scan_phase1(
        const int* __restrict__ deg, int* __restrict__ partial,
        int* __restrict__ blocksum, int n) {
    __shared__ int tmp[1024];
    const int tid = threadIdx.x;
    int i = blockIdx.x * 1024 + tid;
    int v = (i < n) ? deg[i] : 0;
    tmp[tid] = v;
    __syncthreads();
    #pragma unroll
    for (int off = 1; off < 1024; off <<= 1) {
        int t = (tid >= off) ? tmp[tid - off] : 0;
        __syncthreads();
        tmp[tid] += t;
        __syncthreads();
    }
    if (i < n) partial[i] = tmp[tid];
    if (tid == 1023) blocksum[blockIdx.x] = tmp[1023];
}

// phase3 computes its own blocksum prefix (nb_scan <= 64)
__global__ __launch_bounds__(1024) void scan_phase3(
        const int* __restrict__ partial, const int* __restrict__ blocksum,
        const int* __restrict__ deg, int* __restrict__ rowptr,
        int* __restrict__ degcur, int n) {
    __shared__ int add_s;
    if (threadIdx.x < 64) {
        int lane = threadIdx.x;
        int v = (lane < (int)blockIdx.x) ? blocksum[lane] : 0;
        #pragma unroll
        for (int off = 32; off > 0; off >>= 1) v += __shfl_down(v, off, 64);
        if (lane == 0) add_s = v;
    }
    __syncthreads();
    const int add = add_s;
    int i = blockIdx.x * 1024 + threadIdx.x;
    if (i >= n) return;
    int incl = partial[i] + add;
    rowptr[i + 1] = incl;
    degcur[i] = incl - deg[i];
    if (i == 0) rowptr[0] = 0;
}

__global__ __launch_bounds__(256) void fill_kernel(
        const int* __restrict__ src, const int* __restrict__ dst,
        int* __restrict__ cursor, int* __restrict__ srcs_csr, int ne) {
    int e = blockIdx.x * 256 + threadIdx.x;
    if (e >= ne) return;
    int pos = atomicAdd(cursor + dst[e], 1);
    srcs_csr[pos] = src[e];
}

// ---------------- dual MFMA GEMM (f16 in, fp8 O1 / f16 O2), 64-row blocks --
template <int K>
__global__ __launch_bounds__(256) void gemm_dual_mfma(
        const f16* __restrict__ A, const f16* __restrict__ Wp1,
        const f16* __restrict__ Wp2, const float* __restrict__ bias1,
        const float* __restrict__ bias2, u8* __restrict__ O1,
        f16* __restrict__ O2, int n) {
    constexpr int KT = K / 32;
    const int lane = threadIdx.x & 63;
    const int w    = threadIdx.x >> 6;
    const int row0 = blockIdx.x * 64;
    const int col0 = w * 64;

    f32x4 acc1[4][4], acc2[4][4];
    const f32x4 zero = {0.f, 0.f, 0.f, 0.f};
    #pragma unroll
    for (int i = 0; i < 4; ++i)
        #pragma unroll
        for (int j = 0; j < 4; ++j) { acc1[i][j] = zero; acc2[i][j] = zero; }

    const f16* Arow[4];
    #pragma unroll
    for (int rf = 0; rf < 4; ++rf) {
        int ar = min(row0 + rf * 16 + (lane & 15), n - 1);
        Arow[rf] = A + (size_t)ar * K + (lane >> 4) * 8;
    }
    const f16* Wb1 = Wp1 + ((size_t)(w * 4) * 64 + lane) * 8;
    const f16* Wb2 = Wp2 + ((size_t)(w * 4) * 64 + lane) * 8;

    #pragma unroll
    for (int kt = 0; kt < KT; ++kt) {
        f16x8 a[4];
        #pragma unroll
        for (int rf = 0; rf < 4; ++rf)
            a[rf] = *reinterpret_cast<const f16x8*>(Arow[rf] + kt * 32);
        #pragma unroll
        for (int cf = 0; cf < 4; ++cf) {
            f16x8 b1v = *reinterpret_cast<const f16x8*>(Wb1 + (size_t)(kt * 16 + cf) * 512);
            f16x8 b2v = *reinterpret_cast<const f16x8*>(Wb2 + (size_t)(kt * 16 + cf) * 512);
            #pragma unroll
            for (int rf = 0; rf < 4; ++rf) {
                acc1[rf][cf] = __builtin_amdgcn_mfma_f32_16x16x32_f16(a[rf], b1v, acc1[rf][cf], 0, 0, 0);
                acc2[rf][cf] = __builtin_amdgcn_mfma_f32_16x16x32_f16(a[rf], b2v, acc2[rf][cf], 0, 0, 0);
            }
        }
    }

    #pragma unroll
    for (int cf = 0; cf < 4; ++cf) {
        const int col = col0 + cf * 16 + (lane & 15);
        const float bsum = bias1[col] + bias2[col];
        #pragma unroll
        for (int rf = 0; rf < 4; ++rf) {
            #pragma unroll
            for (int r = 0; r < 4; ++r) {
                const int row = row0 + rf * 16 + (lane >> 4) * 4 + r;
                if (row < n) {
                    O1[(size_t)row * D1 + col] = f2fp8(acc1[rf][cf][r]);
                    O2[(size_t)row * D1 + col] = (f16)(acc2[rf][cf][r] + bsum);
                }
            }
        }
    }
}

// ---------------- fused per-node GAT gather (fp8 xs, round-12 structure) ----
// Head-parallel alpha: 16-edge chunks; lane = h*16+j computes alpha for head h,
// edge j (1 exp/lane). 4B loads, 4 edges in flight. Softmax without
// max-subtraction (shift-invariant; |e| <= ~3 here).
#define ALDS_STRIDE 66

__device__ __forceinline__ float4 gat_node_acc(
        const int* __restrict__ srcs, const float* __restrict__ a_s,
        const u8* __restrict__ xs, f16* __restrict__ alds,
        const float* __restrict__ a_d_row, int base, int deg, int lane) {
    const int h = lane >> 4;
    const int j = lane & 15;
    const float adv = a_d_row[h];
    float den = 0.f;
    float4 acc = {0.f, 0.f, 0.f, 0.f};
    const f16* arow = alds + h * ALDS_STRIDE;

    for (int c0 = 0; c0 < deg; c0 += 16) {
        const int cnt = min(16, deg - c0);
        const int idx = c0 + j;
        const bool valid = idx < deg;
        const int sl = srcs[base + min(idx, deg - 1)];
        {
            float e = a_s[(size_t)sl * 4 + h] + adv;
            e = e > 0.f ? e : 0.2f * e;
            float a = valid ? __expf(e) : 0.f;
            den += a;
            alds[h * ALDS_STRIDE + j] = (f16)a;
        }
        asm volatile("s_waitcnt lgkmcnt(0)" ::: "memory");

        const int sv = sl;   // lanes 0..15 hold this chunk's srcs (dup per head)
        for (int i = 0; i < cnt; i += 4) {
            int s1 = __shfl(sv, i, 64);
            int s2 = __shfl(sv, i + 1, 64);
            int s3 = __shfl(sv, i + 2, 64);
            int s4 = __shfl(sv, i + 3, 64);
            f16x2 alA = *reinterpret_cast<const f16x2*>(arow + i);
            f16x2 alB = *reinterpret_cast<const f16x2*>(arow + i + 2);
            unsigned x1 = *reinterpret_cast<const unsigned*>(xs + (size_t)s1 * D1 + lane * 4);
            unsigned x2 = *reinterpret_cast<const unsigned*>(xs + (size_t)s2 * D1 + lane * 4);
            unsigned x3 = *reinterpret_cast<const unsigned*>(xs + (size_t)s3 * D1 + lane * 4);
            unsigned x4 = *reinterpret_cast<const unsigned*>(xs + (size_t)s4 * D1 + lane * 4);
            fp8fma(x1, (float)alA.x, acc);
            fp8fma(x2, (float)alA.y, acc);
            fp8fma(x3, (float)alB.x, acc);
            fp8fma(x4, (float)alB.y, acc);
        }
    }

    // den reduce within 16-lane head group (lane's den is its own head's)
    #pragma unroll
    for (int off = 1; off < 16; off <<= 1)
        den += __shfl_xor(den, off, 64);
    const float invd = 1.f / (den + 1e-16f);
    acc.x *= invd; acc.y *= invd; acc.z *= invd; acc.w *= invd;
    return acc;
}

// layer-1: h = relu(LN(gather + skip)) -> f16, plus layer-2 scores epilogue
__global__ __launch_bounds__(256) void gat_gather_ln_kernel(
        const int* __restrict__ rowptr, const int* __restrict__ srcs,
        const float* __restrict__ a_s1, const float* __restrict__ a_d1,
        const u8* __restrict__ xs, const f16* __restrict__ skip,
        const float* __restrict__ gamma, const float* __restrict__ beta,
        const float* __restrict__ Vs2, const float* __restrict__ Vd2,
        f16* __restrict__ hout, float* __restrict__ a_s2,
        float* __restrict__ a_d2, int n) {
    __shared__ f16 alpha_lds[4][4 * ALDS_STRIDE];
    const int wid = threadIdx.x >> 6, lane = threadIdx.x & 63;
    const int d = blockIdx.x * 4 + wid;
    if (d >= n) return;
    const int base = rowptr[d];
    const int deg  = rowptr[d + 1] - base;

    float4 acc = {0.f, 0.f, 0.f, 0.f};
    if (deg > 0)
        acc = gat_node_acc(srcs, a_s1, xs, alpha_lds[wid],
                           a_d1 + (size_t)d * 4, base, deg, lane);

    f16x4 sk = *reinterpret_cast<const f16x4*>(skip + (size_t)d * D1 + lane * 4);
    float4 v;
    v.x = acc.x + (float)sk[0];
    v.y = acc.y + (float)sk[1];
    v.z = acc.z + (float)sk[2];
    v.w = acc.w + (float)sk[3];

    float s  = v.x + v.y + v.z + v.w;
    float sq = v.x * v.x + v.y * v.y + v.z * v.z + v.w * v.w;
    #pragma unroll
    for (int off = 32; off > 0; off >>= 1) {
        s  += __shfl_down(s, off, 64);
        sq += __shfl_down(sq, off, 64);
    }
    s  = __shfl(s, 0, 64);
    sq = __shfl(sq, 0, 64);
    float mu  = s * (1.f / 256.f);
    float var = sq * (1.f / 256.f) - mu * mu;
    float rstd = rsqrtf(var + 1e-5f);
    float4 g = *reinterpret_cast<const float4*>(gamma + lane * 4);
    float4 b = *reinterpret_cast<const float4*>(beta + lane * 4);
    f16x4 o;
    o[0] = (f16)fmaxf((v.x - mu) * rstd * g.x + b.x, 0.f);
    o[1] = (f16)fmaxf((v.y - mu) * rstd * g.y + b.y, 0.f);
    o[2] = (f16)fmaxf((v.z - mu) * rstd * g.z + b.z, 0.f);
    o[3] = (f16)fmaxf((v.w - mu) * rstd * g.w + b.w, 0.f);
    *reinterpret_cast<f16x4*>(hout + (size_t)d * D1 + lane * 4) = o;

    // ---- layer-2 scores epilogue (reduce-scatter, 10 shfl) ----
    float of0 = (float)o[0], of1 = (float)o[1], of2 = (float)o[2], of3 = (float)o[3];
    const float4* V4s = reinterpret_cast<const float4*>(Vs2);
    const float4* V4d = reinterpret_cast<const float4*>(Vd2);
    float4 r0 = V4s[lane * 4 + 0], r1 = V4s[lane * 4 + 1];
    float4 r2 = V4s[lane * 4 + 2], r3 = V4s[lane * 4 + 3];
    float v0 = of0 * r0.x + of1 * r1.x + of2 * r2.x + of3 * r3.x;
    float v1 = of0 * r0.y + of1 * r1.y + of2 * r2.y + of3 * r3.y;
    float v2 = of0 * r0.z + of1 * r1.z + of2 * r2.z + of3 * r3.z;
    float v3 = of0 * r0.w + of1 * r1.w + of2 * r2.w + of3 * r3.w;
    r0 = V4d[lane * 4 + 0]; r1 = V4d[lane * 4 + 1];
    r2 = V4d[lane * 4 + 2]; r3 = V4d[lane * 4 + 3];
    float v4 = of0 * r0.x + of1 * r1.x + of2 * r2.x + of3 * r3.x;
    float v5 = of0 * r0.y + of1 * r1.y + of2 * r2.y + of3 * r3.y;
    float v6 = of0 * r0.z + of1 * r1.z + of2 * r2.z + of3 * r3.z;
    float v7 = of0 * r0.w + of1 * r1.w + of2 * r2.w + of3 * r3.w;

    const bool b0 = (lane & 1) != 0;
    float w0 = (b0 ? v1 : v0) + __shfl_xor(b0 ? v0 : v1, 1, 64);
    float w1 = (b0 ? v3 : v2) + __shfl_xor(b0 ? v2 : v3, 1, 64);
    float w2 = (b0 ? v5 : v4) + __shfl_xor(b0 ? v4 : v5, 1, 64);
    float w3 = (b0 ? v7 : v6) + __shfl_xor(b0 ? v6 : v7, 1, 64);
    const bool b1 = (lane & 2) != 0;
    float u0 = (b1 ? w1 : w0) + __shfl_xor(b1 ? w0 : w1, 2, 64);
    float u1 = (b1 ? w3 : w2) + __shfl_xor(b1 ? w2 : w3, 2, 64);
    const bool b2f = (lane & 4) != 0;
    float z = (b2f ? u1 : u0) + __shfl_xor(b2f ? u0 : u1, 4, 64);
    z += __shfl_xor(z, 8, 64);
    z += __shfl_xor(z, 16, 64);
    z += __shfl_xor(z, 32, 64);
    // lane l (l<8) now holds total of value index l: 0-3 -> a_s2, 4-7 -> a_d2
    if (lane < 8) {
        float* outp = (lane < 4) ? (a_s2 + (size_t)d * 4 + lane)
                                 : (a_d2 + (size_t)d * 4 + (lane - 4));
        *outp = z;
    }
}

// layer-2: out = gather + skip2 (write-once fp32, no RMW)
__global__ __launch_bounds__(256) void gat_gather_out_kernel(
        const int* __restrict__ rowptr, const int* __restrict__ srcs,
        const float* __restrict__ a_s, const float* __restrict__ a_d,
        const u8* __restrict__ xs, const f16* __restrict__ skip2,
        float* __restrict__ out, int n) {
    __shared__ f16 alpha_lds[4][4 * ALDS_STRIDE];
    const int wid = threadIdx.x >> 6, lane = threadIdx.x & 63;
    const int d = blockIdx.x * 4 + wid;
    if (d >= n) return;
    const int base = rowptr[d];
    const int deg  = rowptr[d + 1] - base;
    float4 acc = {0.f, 0.f, 0.f, 0.f};
    if (deg > 0)
        acc = gat_node_acc(srcs, a_s, xs, alpha_lds[wid],
                           a_d + (size_t)d * 4, base, deg, lane);
    f16x4 sk = *reinterpret_cast<const f16x4*>(skip2 + (size_t)d * D1 + lane * 4);
    float4 ov;
    ov.x = acc.x + (float)sk[0];
    ov.y = acc.y + (float)sk[1];
    ov.z = acc.z + (float)sk[2];
    ov.w = acc.w + (float)sk[3];
    *reinterpret_cast<float4*>(out + (size_t)d * D1 + lane * 4) = ov;
}

extern "C" void kernel_launch(void* const* d_in, const int* in_sizes, int n_in,
                              void* d_out, int out_size, void* d_ws, size_t ws_size,
                              hipStream_t stream) {
    const float* x     = (const float*)d_in[0];
    const int*   ei    = (const int*)d_in[1];
    const float* Wsrc1 = (const float*)d_in[2];
    const float* Wdst1 = (const float*)d_in[3];
    const float* atts1 = (const float*)d_in[4];
    const float* attd1 = (const float*)d_in[5];
    const float* b1    = (const float*)d_in[6];
    const float* Wlin1 = (const float*)d_in[7];
    const float* blin1 = (const float*)d_in[8];
    const float* gamma = (const float*)d_in[9];
    const float* beta  = (const float*)d_in[10];
    const float* Wsrc2 = (const float*)d_in[11];
    const float* Wdst2 = (const float*)d_in[12];
    const float* atts2 = (const float*)d_in[13];
    const float* attd2 = (const float*)d_in[14];
    const float* b2    = (const float*)d_in[15];
    const float* Wlin2 = (const float*)d_in[16];
    const float* blin2 = (const float*)d_in[17];

    const int n  = in_sizes[0] / DIN;   // 50000
    const int ne = in_sizes[1] / 2;     // 800000
    const int* src = ei;
    const int* dst = ei + ne;

    char* w8 = (char*)d_ws;
    size_t off = 0;
    auto alloc = [&](size_t bytes) -> void* {
        void* p = w8 + off;
        off += (bytes + 255) & ~(size_t)255;
        return p;
    };
    f16*  h16    = (f16*)alloc((size_t)n * D1 * 2);
    f16*  x16    = h16;   // union: x16 dead before gather_ln writes h16
    u8*   xs8    = (u8*)alloc((size_t)n * D1);
    f16*  skip1  = (f16*)alloc((size_t)n * D1 * 2);   // reused as skip2
    float* a_s1  = (float*)alloc((size_t)n * HH * 4);
    float* a_d1  = (float*)alloc((size_t)n * HH * 4);
    float* a_s2  = (float*)alloc((size_t)n * HH * 4);
    float* a_d2  = (float*)alloc((size_t)n * HH * 4);
    float* Vs1   = (float*)alloc((size_t)D1 * HH * 4);
    float* Vd1   = (float*)alloc((size_t)D1 * HH * 4);
    float* Vs2   = (float*)alloc((size_t)D1 * HH * 4);
    float* Vd2   = (float*)alloc((size_t)D1 * HH * 4);
    int* rowptr   = (int*)alloc(((size_t)n + 1) * 4);
    int* degbuf   = (int*)alloc((size_t)n * 4);
    int* degcur   = (int*)alloc((size_t)n * 4);
    int* partial  = (int*)alloc((size_t)n * 4);
    int* blocksum = (int*)alloc(1024 * 4);
    int* srcs_csr = (int*)alloc((size_t)ne * 4);
    f16* WpS1  = (f16*)alloc((size_t)DIN * D1 * 2);
    f16* WpL1  = (f16*)alloc((size_t)DIN * D1 * 2);
    f16* WpS2  = (f16*)alloc((size_t)D1 * D1 * 2);
    f16* WpL2  = (f16*)alloc((size_t)D1 * D1 * 2);

    float* out = (float*)d_out;

    const int nb_node4  = (n + 3) / 4;
    const int nb_node64 = (n + 63) / 64;
    const int nb_e      = (ne + 255) / 256;
    const int nb_gemm   = (n + 63) / 64;
    const int nb_scan   = (n + 1023) / 1024;
    const int nb_pack   = (DIN * D1 + D1 * D1 + 255) / 256;

    // ---------------- prep ----------------
    (void)hipMemsetAsync(degbuf, 0, (size_t)n * 4, stream);
    deg_kernel<<<nb_e, 256, 0, stream>>>(dst, degbuf, ne);
    scan_phase1<<<nb_scan, 1024, 0, stream>>>(degbuf, partial, blocksum, n);
    scan_phase3<<<nb_scan, 1024, 0, stream>>>(partial, blocksum, degbuf, rowptr, degcur, n);
    fill_kernel<<<nb_e, 256, 0, stream>>>(src, dst, degcur, srcs_csr, ne);
    prep_w_kernel<<<nb_pack + 2 * (DIN + D1), 256, 0, stream>>>(
        Wsrc1, Wlin1, Wsrc2, Wlin2, Wdst1, Wdst2,
        atts1, attd1, atts2, attd2,
        WpS1, WpL1, WpS2, WpL2, Vs1, Vd1, Vs2, Vd2, nb_pack);

    // ---------------- layer 1 ----------------
    cvt_scores_kernel<<<nb_node64, 256, 0, stream>>>(x, Vs1, Vd1, x16, a_s1, a_d1, n);
    gemm_dual_mfma<DIN><<<nb_gemm, 256, 0, stream>>>(x16, WpS1, WpL1, b1, blin1, xs8, skip1, n);
    gat_gather_ln_kernel<<<nb_node4, 256, 0, stream>>>(rowptr, srcs_csr, a_s1, a_d1, xs8,
                                                       skip1, gamma, beta, Vs2, Vd2,
                                                       h16, a_s2, a_d2, n);

    // ---------------- layer 2 ----------------
    gemm_dual_mfma<D1><<<nb_gemm, 256, 0, stream>>>(h16, WpS2, WpL2, b2, blin2, xs8, skip1, n);
    gat_gather_out_kernel<<<nb_node4, 256, 0, stream>>>(rowptr, srcs_csr, a_s2, a_d2,
                                                        xs8, skip1, out, n);
}

// Round 15
// 272.445 us; speedup vs baseline: 1.0624x; 1.0280x over previous
//
#include <hip/hip_runtime.h>
#include <float.h>

constexpr int DIN = 128;
constexpr int D1  = 256;
constexpr int HH  = 4;
constexpr int CC  = 64;

typedef _Float16 f16;
typedef __attribute__((ext_vector_type(2))) _Float16 f16x2;
typedef __attribute__((ext_vector_type(4))) _Float16 f16x4;
typedef __attribute__((ext_vector_type(8))) _Float16 f16x8;
typedef __attribute__((ext_vector_type(2))) float f32x2;
typedef __attribute__((ext_vector_type(4))) float f32x4;
typedef unsigned char u8;

#if __has_builtin(__builtin_amdgcn_cvt_pk_f32_fp8) && __has_builtin(__builtin_amdgcn_cvt_pk_fp8_f32)
#define HAS_CVT_FP8 1
#else
#define HAS_CVT_FP8 0
#include <hip/hip_fp8.h>
#endif

__device__ __forceinline__ u8 f2fp8(float f) {
#if HAS_CVT_FP8
    return (u8)(__builtin_amdgcn_cvt_pk_fp8_f32(f, f, 0, false) & 0xff);
#else
    __hip_fp8_e4m3 t(f);
    return (u8)t.__x;
#endif
}

__device__ __forceinline__ void fp8fma(unsigned w, float a, float4& acc) {
#if HAS_CVT_FP8
    f32x2 lo = __builtin_amdgcn_cvt_pk_f32_fp8((int)w, false);
    f32x2 hi = __builtin_amdgcn_cvt_pk_f32_fp8((int)w, true);
    acc.x = fmaf(lo[0], a, acc.x);
    acc.y = fmaf(lo[1], a, acc.y);
    acc.z = fmaf(hi[0], a, acc.z);
    acc.w = fmaf(hi[1], a, acc.w);
#else
    __hip_fp8_e4m3 b0, b1, b2, b3;
    b0.__x = (w) & 0xff; b1.__x = (w >> 8) & 0xff;
    b2.__x = (w >> 16) & 0xff; b3.__x = (w >> 24) & 0xff;
    acc.x = fmaf((float)b0, a, acc.x);
    acc.y = fmaf((float)b1, a, acc.y);
    acc.z = fmaf((float)b2, a, acc.z);
    acc.w = fmaf((float)b3, a, acc.w);
#endif
}

__device__ __forceinline__ float wave_sum(float v) {
    #pragma unroll
    for (int off = 32; off > 0; off >>= 1) v += __shfl_down(v, off, 64);
    return v;
}

// ---------------- fused W prep (pack + make_v) + deg histogram ----------------
// blocks [0, nb_pack): pack_w. blocks [nb_pack, nb_pack+2*(DIN+D1)): make_v.
// blocks beyond: deg histogram (independent of W).
__global__ __launch_bounds__(256) void prep_deg_kernel(
        const float* __restrict__ Wsrc1, const float* __restrict__ Wlin1,
        const float* __restrict__ Wsrc2, const float* __restrict__ Wlin2,
        const float* __restrict__ Wdst1, const float* __restrict__ Wdst2,
        const float* __restrict__ atts1, const float* __restrict__ attd1,
        const float* __restrict__ atts2, const float* __restrict__ attd2,
        f16* __restrict__ WpS1, f16* __restrict__ WpL1,
        f16* __restrict__ WpS2, f16* __restrict__ WpL2,
        float* __restrict__ Vs1, float* __restrict__ Vd1,
        float* __restrict__ Vs2, float* __restrict__ Vd2,
        const int* __restrict__ dst, int* __restrict__ deg, int ne,
        int nb_pack, int nb_v) {
    int bid = blockIdx.x;
    if (bid < nb_pack) {
        int idx = bid * 256 + threadIdx.x;
        const float *Wa, *Wb;
        f16 *Wpa, *Wpb;
        if (idx < DIN * D1) { Wa = Wsrc1; Wb = Wlin1; Wpa = WpS1; Wpb = WpL1; }
        else {
            idx -= DIN * D1;
            if (idx >= D1 * D1) return;
            Wa = Wsrc2; Wb = Wlin2; Wpa = WpS2; Wpb = WpL2;
        }
        int j    = idx & 7;
        int lane = (idx >> 3) & 63;
        int t    = idx >> 9;
        int ct   = t & 15, kt = t >> 4;
        int k    = kt * 32 + (lane >> 4) * 8 + j;
        int col  = ct * 16 + (lane & 15);
        size_t widx = (size_t)k * D1 + col;
        Wpa[idx] = (f16)Wa[widx];
        Wpb[idx] = (f16)Wb[widx];
        return;
    }
    bid -= nb_pack;
    if (bid < nb_v) {
        int mat = bid & 1;
        int kb  = bid >> 1;
        int h = threadIdx.x >> 6, lane = threadIdx.x & 63;
        const float *W, *att;
        float* V;
        int k;
        if (kb < DIN) {
            k = kb;
            W = mat ? Wdst1 : Wsrc1; att = mat ? attd1 : atts1; V = mat ? Vd1 : Vs1;
        } else {
            k = kb - DIN;
            W = mat ? Wdst2 : Wsrc2; att = mat ? attd2 : atts2; V = mat ? Vd2 : Vs2;
        }
        float v = W[(size_t)k * D1 + h * CC + lane] * att[h * CC + lane];
        v = wave_sum(v);
        if (lane == 0) V[k * HH + h] = v;
        return;
    }
    bid -= nb_v;
    int e = bid * 256 + threadIdx.x;
    if (e < ne) atomicAdd(deg + dst[e], 1);
}

// ---------------- fused fp32->f16 convert + layer-1 scores + scan1 ---------
// blocks [0, nb_cvt): cvt+scores (needs Vs1/Vd1). blocks beyond: scan phase 1.
__global__ __launch_bounds__(1024) void cvt_scores_scan1_kernel(
        const float* __restrict__ X, const float* __restrict__ Vs,
        const float* __restrict__ Vd, f16* __restrict__ X16,
        float* __restrict__ a_s, float* __restrict__ a_d, int n,
        const int* __restrict__ deg, int* __restrict__ partial,
        int* __restrict__ blocksum, int nb_cvt) {
    __shared__ int tmp[1024];
    if ((int)blockIdx.x >= nb_cvt) {
        // ---- scan phase 1 (1024 threads) ----
        const int sb = blockIdx.x - nb_cvt;
        const int tid = threadIdx.x;
        int i = sb * 1024 + tid;
        int v = (i < n) ? deg[i] : 0;
        tmp[tid] = v;
        __syncthreads();
        #pragma unroll
        for (int off = 1; off < 1024; off <<= 1) {
            int t = (tid >= off) ? tmp[tid - off] : 0;
            __syncthreads();
            tmp[tid] += t;
            __syncthreads();
        }
        if (i < n) partial[i] = tmp[tid];
        if (tid == 1023) blocksum[sb] = tmp[1023];
        return;
    }
    // ---- cvt + scores (only threads < 256 active) ----
    if (threadIdx.x >= 256) return;
    constexpr int K = DIN, C = 32, SH = 5;
    float4* VsL = reinterpret_cast<float4*>(tmp);            // reuse LDS
    __shared__ float4 VdL[K + 4];
    for (int k = threadIdx.x; k < K; k += 256) {
        int ki = k + (k >> SH);
        VsL[ki] = reinterpret_cast<const float4*>(Vs)[k];
        VdL[ki] = reinterpret_cast<const float4*>(Vd)[k];
    }
    __syncthreads();

    const int lane  = threadIdx.x & 63;
    const int wid   = threadIdx.x >> 6;
    const int node  = blockIdx.x * 64 + wid * 16 + (lane >> 2);
    const int chunk = lane & 3;
    const int nodec = min(node, n - 1);
    const float* xp = X + (size_t)nodec * K + chunk * C;

    float xv[C];
    #pragma unroll
    for (int b = 0; b < C / 4; ++b) {
        float4 v = reinterpret_cast<const float4*>(xp)[b];
        xv[b * 4 + 0] = v.x; xv[b * 4 + 1] = v.y;
        xv[b * 4 + 2] = v.z; xv[b * 4 + 3] = v.w;
    }
    if (node < n) {
        f16* op = X16 + (size_t)node * K + chunk * C;
        #pragma unroll
        for (int b = 0; b < C / 8; ++b) {
            f16x8 o;
            #pragma unroll
            for (int t = 0; t < 8; ++t) o[t] = (f16)xv[b * 8 + t];
            reinterpret_cast<f16x8*>(op)[b] = o;
        }
    }

    float ps0 = 0.f, ps1 = 0.f, ps2 = 0.f, ps3 = 0.f;
    float pd0 = 0.f, pd1 = 0.f, pd2 = 0.f, pd3 = 0.f;
    #pragma unroll
    for (int t = 0; t < C; ++t) {
        int k  = chunk * C + t;
        int ki = k + (k >> SH);
        float xf = xv[t];
        float4 vs = VsL[ki];
        float4 vd = VdL[ki];
        ps0 = fmaf(xf, vs.x, ps0); ps1 = fmaf(xf, vs.y, ps1);
        ps2 = fmaf(xf, vs.z, ps2); ps3 = fmaf(xf, vs.w, ps3);
        pd0 = fmaf(xf, vd.x, pd0); pd1 = fmaf(xf, vd.y, pd1);
        pd2 = fmaf(xf, vd.z, pd2); pd3 = fmaf(xf, vd.w, pd3);
    }
    #pragma unroll
    for (int off = 1; off <= 2; off <<= 1) {
        ps0 += __shfl_xor(ps0, off, 64); ps1 += __shfl_xor(ps1, off, 64);
        ps2 += __shfl_xor(ps2, off, 64); ps3 += __shfl_xor(ps3, off, 64);
        pd0 += __shfl_xor(pd0, off, 64); pd1 += __shfl_xor(pd1, off, 64);
        pd2 += __shfl_xor(pd2, off, 64); pd3 += __shfl_xor(pd3, off, 64);
    }
    if (node < n) {
        float psv = chunk == 0 ? ps0 : chunk == 1 ? ps1 : chunk == 2 ? ps2 : ps3;
        float pdv = chunk == 0 ? pd0 : chunk == 1 ? pd1 : chunk == 2 ? pd2 : pd3;
        a_s[node * 4 + chunk] = psv;
        a_d[node * 4 + chunk] = pdv;
    }
}

// phase3 computes its own blocksum prefix (nb_scan <= 64)
__global__ __launch_bounds__(1024) void scan_phase3(
        const int* __restrict__ partial, const int* __restrict__ blocksum,
        const int* __restrict__ deg, int* __restrict__ rowptr,
        int* __restrict__ degcur, int n) {
    __shared__ int add_s;
    if (threadIdx.x < 64) {
        int lane = threadIdx.x;
        int v = (lane < (int)blockIdx.x) ? blocksum[lane] : 0;
        #pragma unroll
        for (int off = 32; off > 0; off >>= 1) v += __shfl_down(v, off, 64);
        if (lane == 0) add_s = v;
    }
    __syncthreads();
    const int add = add_s;
    int i = blockIdx.x * 1024 + threadIdx.x;
    if (i >= n) return;
    int incl = partial[i] + add;
    rowptr[i + 1] = incl;
    degcur[i] = incl - deg[i];
    if (i == 0) rowptr[0] = 0;
}

__global__ __launch_bounds__(256) void fill_kernel(
        const int* __restrict__ src, const int* __restrict__ dst,
        int* __restrict__ cursor, int* __restrict__ srcs_csr, int ne) {
    int e = blockIdx.x * 256 + threadIdx.x;
    if (e >= ne) return;
    int pos = atomicAdd(cursor + dst[e], 1);
    srcs_csr[pos] = src[e];
}

// ---------------- dual MFMA GEMM (f16 in, fp8 O1 / f16 O2), 64-row blocks --
template <int K>
__global__ __launch_bounds__(256) void gemm_dual_mfma(
        const f16* __restrict__ A, const f16* __restrict__ Wp1,
        const f16* __restrict__ Wp2, const float* __restrict__ bias1,
        const float* __restrict__ bias2, u8* __restrict__ O1,
        f16* __restrict__ O2, int n) {
    constexpr int KT = K / 32;
    const int lane = threadIdx.x & 63;
    const int w    = threadIdx.x >> 6;
    const int row0 = blockIdx.x * 64;
    const int col0 = w * 64;

    f32x4 acc1[4][4], acc2[4][4];
    const f32x4 zero = {0.f, 0.f, 0.f, 0.f};
    #pragma unroll
    for (int i = 0; i < 4; ++i)
        #pragma unroll
        for (int j = 0; j < 4; ++j) { acc1[i][j] = zero; acc2[i][j] = zero; }

    const f16* Arow[4];
    #pragma unroll
    for (int rf = 0; rf < 4; ++rf) {
        int ar = min(row0 + rf * 16 + (lane & 15), n - 1);
        Arow[rf] = A + (size_t)ar * K + (lane >> 4) * 8;
    }
    const f16* Wb1 = Wp1 + ((size_t)(w * 4) * 64 + lane) * 8;
    const f16* Wb2 = Wp2 + ((size_t)(w * 4) * 64 + lane) * 8;

    #pragma unroll
    for (int kt = 0; kt < KT; ++kt) {
        f16x8 a[4];
        #pragma unroll
        for (int rf = 0; rf < 4; ++rf)
            a[rf] = *reinterpret_cast<const f16x8*>(Arow[rf] + kt * 32);
        #pragma unroll
        for (int cf = 0; cf < 4; ++cf) {
            f16x8 b1v = *reinterpret_cast<const f16x8*>(Wb1 + (size_t)(kt * 16 + cf) * 512);
            f16x8 b2v = *reinterpret_cast<const f16x8*>(Wb2 + (size_t)(kt * 16 + cf) * 512);
            #pragma unroll
            for (int rf = 0; rf < 4; ++rf) {
                acc1[rf][cf] = __builtin_amdgcn_mfma_f32_16x16x32_f16(a[rf], b1v, acc1[rf][cf], 0, 0, 0);
                acc2[rf][cf] = __builtin_amdgcn_mfma_f32_16x16x32_f16(a[rf], b2v, acc2[rf][cf], 0, 0, 0);
            }
        }
    }

    #pragma unroll
    for (int cf = 0; cf < 4; ++cf) {
        const int col = col0 + cf * 16 + (lane & 15);
        const float bsum = bias1[col] + bias2[col];
        #pragma unroll
        for (int rf = 0; rf < 4; ++rf) {
            #pragma unroll
            for (int r = 0; r < 4; ++r) {
                const int row = row0 + rf * 16 + (lane >> 4) * 4 + r;
                if (row < n) {
                    O1[(size_t)row * D1 + col] = f2fp8(acc1[rf][cf][r]);
                    O2[(size_t)row * D1 + col] = (f16)(acc2[rf][cf][r] + bsum);
                }
            }
        }
    }
}

// ---------------- fused per-node GAT gather (fp8 xs) ----------------
#define ALDS_STRIDE 66

__device__ __forceinline__ float4 gat_node_acc(
        const int* __restrict__ srcs, const float* __restrict__ a_s,
        const u8* __restrict__ xs, f16* __restrict__ alds,
        const float* __restrict__ a_d_row, int base, int deg, int lane) {
    const int h = lane >> 4;
    const int j = lane & 15;
    const float adv = a_d_row[h];
    float den = 0.f;
    float4 acc = {0.f, 0.f, 0.f, 0.f};
    const f16* arow = alds + h * ALDS_STRIDE;

    for (int c0 = 0; c0 < deg; c0 += 16) {
        const int cnt = min(16, deg - c0);
        const int idx = c0 + j;
        const bool valid = idx < deg;
        const int sl = srcs[base + min(idx, deg - 1)];
        {
            float e = a_s[(size_t)sl * 4 + h] + adv;
            e = e > 0.f ? e : 0.2f * e;
            float a = valid ? __expf(e) : 0.f;
            den += a;
            alds[h * ALDS_STRIDE + j] = (f16)a;
        }
        asm volatile("s_waitcnt lgkmcnt(0)" ::: "memory");

        const int sv = sl;
        for (int i = 0; i < cnt; i += 4) {
            int s1 = __shfl(sv, i, 64);
            int s2 = __shfl(sv, i + 1, 64);
            int s3 = __shfl(sv, i + 2, 64);
            int s4 = __shfl(sv, i + 3, 64);
            f16x2 alA = *reinterpret_cast<const f16x2*>(arow + i);
            f16x2 alB = *reinterpret_cast<const f16x2*>(arow + i + 2);
            unsigned x1 = *reinterpret_cast<const unsigned*>(xs + (size_t)s1 * D1 + lane * 4);
            unsigned x2 = *reinterpret_cast<const unsigned*>(xs + (size_t)s2 * D1 + lane * 4);
            unsigned x3 = *reinterpret_cast<const unsigned*>(xs + (size_t)s3 * D1 + lane * 4);
            unsigned x4 = *reinterpret_cast<const unsigned*>(xs + (size_t)s4 * D1 + lane * 4);
            fp8fma(x1, (float)alA.x, acc);
            fp8fma(x2, (float)alA.y, acc);
            fp8fma(x3, (float)alB.x, acc);
            fp8fma(x4, (float)alB.y, acc);
        }
    }

    #pragma unroll
    for (int off = 1; off < 16; off <<= 1)
        den += __shfl_xor(den, off, 64);
    const float invd = 1.f / (den + 1e-16f);
    acc.x *= invd; acc.y *= invd; acc.z *= invd; acc.w *= invd;
    return acc;
}

// layer-1: h = relu(LN(gather + skip)) -> f16, plus layer-2 scores epilogue
__global__ __launch_bounds__(256) void gat_gather_ln_kernel(
        const int* __restrict__ rowptr, const int* __restrict__ srcs,
        const float* __restrict__ a_s1, const float* __restrict__ a_d1,
        const u8* __restrict__ xs, const f16* __restrict__ skip,
        const float* __restrict__ gamma, const float* __restrict__ beta,
        const float* __restrict__ Vs2, const float* __restrict__ Vd2,
        f16* __restrict__ hout, float* __restrict__ a_s2,
        float* __restrict__ a_d2, int n) {
    __shared__ f16 alpha_lds[4][4 * ALDS_STRIDE];
    const int wid = threadIdx.x >> 6, lane = threadIdx.x & 63;
    const int d = blockIdx.x * 4 + wid;
    if (d >= n) return;
    const int base = rowptr[d];
    const int deg  = rowptr[d + 1] - base;

    float4 acc = {0.f, 0.f, 0.f, 0.f};
    if (deg > 0)
        acc = gat_node_acc(srcs, a_s1, xs, alpha_lds[wid],
                           a_d1 + (size_t)d * 4, base, deg, lane);

    f16x4 sk = *reinterpret_cast<const f16x4*>(skip + (size_t)d * D1 + lane * 4);
    float4 v;
    v.x = acc.x + (float)sk[0];
    v.y = acc.y + (float)sk[1];
    v.z = acc.z + (float)sk[2];
    v.w = acc.w + (float)sk[3];

    float s  = v.x + v.y + v.z + v.w;
    float sq = v.x * v.x + v.y * v.y + v.z * v.z + v.w * v.w;
    #pragma unroll
    for (int off = 32; off > 0; off >>= 1) {
        s  += __shfl_down(s, off, 64);
        sq += __shfl_down(sq, off, 64);
    }
    s  = __shfl(s, 0, 64);
    sq = __shfl(sq, 0, 64);
    float mu  = s * (1.f / 256.f);
    float var = sq * (1.f / 256.f) - mu * mu;
    float rstd = rsqrtf(var + 1e-5f);
    float4 g = *reinterpret_cast<const float4*>(gamma + lane * 4);
    float4 b = *reinterpret_cast<const float4*>(beta + lane * 4);
    f16x4 o;
    o[0] = (f16)fmaxf((v.x - mu) * rstd * g.x + b.x, 0.f);
    o[1] = (f16)fmaxf((v.y - mu) * rstd * g.y + b.y, 0.f);
    o[2] = (f16)fmaxf((v.z - mu) * rstd * g.z + b.z, 0.f);
    o[3] = (f16)fmaxf((v.w - mu) * rstd * g.w + b.w, 0.f);
    *reinterpret_cast<f16x4*>(hout + (size_t)d * D1 + lane * 4) = o;

    // ---- layer-2 scores epilogue (reduce-scatter) ----
    float of0 = (float)o[0], of1 = (float)o[1], of2 = (float)o[2], of3 = (float)o[3];
    const float4* V4s = reinterpret_cast<const float4*>(Vs2);
    const float4* V4d = reinterpret_cast<const float4*>(Vd2);
    float4 r0 = V4s[lane * 4 + 0], r1 = V4s[lane * 4 + 1];
    float4 r2 = V4s[lane * 4 + 2], r3 = V4s[lane * 4 + 3];
    float v0 = of0 * r0.x + of1 * r1.x + of2 * r2.x + of3 * r3.x;
    float v1 = of0 * r0.y + of1 * r1.y + of2 * r2.y + of3 * r3.y;
    float v2 = of0 * r0.z + of1 * r1.z + of2 * r2.z + of3 * r3.z;
    float v3 = of0 * r0.w + of1 * r1.w + of2 * r2.w + of3 * r3.w;
    r0 = V4d[lane * 4 + 0]; r1 = V4d[lane * 4 + 1];
    r2 = V4d[lane * 4 + 2]; r3 = V4d[lane * 4 + 3];
    float v4 = of0 * r0.x + of1 * r1.x + of2 * r2.x + of3 * r3.x;
    float v5 = of0 * r0.y + of1 * r1.y + of2 * r2.y + of3 * r3.y;
    float v6 = of0 * r0.z + of1 * r1.z + of2 * r2.z + of3 * r3.z;
    float v7 = of0 * r0.w + of1 * r1.w + of2 * r2.w + of3 * r3.w;

    const bool bb0 = (lane & 1) != 0;
    float w0 = (bb0 ? v1 : v0) + __shfl_xor(bb0 ? v0 : v1, 1, 64);
    float w1 = (bb0 ? v3 : v2) + __shfl_xor(bb0 ? v2 : v3, 1, 64);
    float w2 = (bb0 ? v5 : v4) + __shfl_xor(bb0 ? v4 : v5, 1, 64);
    float w3 = (bb0 ? v7 : v6) + __shfl_xor(bb0 ? v6 : v7, 1, 64);
    const bool bb1 = (lane & 2) != 0;
    float u0 = (bb1 ? w1 : w0) + __shfl_xor(bb1 ? w0 : w1, 2, 64);
    float u1 = (bb1 ? w3 : w2) + __shfl_xor(bb1 ? w2 : w3, 2, 64);
    const bool bb2 = (lane & 4) != 0;
    float z = (bb2 ? u1 : u0) + __shfl_xor(bb2 ? u0 : u1, 4, 64);
    z += __shfl_xor(z, 8, 64);
    z += __shfl_xor(z, 16, 64);
    z += __shfl_xor(z, 32, 64);
    if (lane < 8) {
        float* outp = (lane < 4) ? (a_s2 + (size_t)d * 4 + lane)
                                 : (a_d2 + (size_t)d * 4 + (lane - 4));
        *outp = z;
    }
}

// layer-2: out = gather + skip2 (write-once fp32, no RMW)
__global__ __launch_bounds__(256) void gat_gather_out_kernel(
        const int* __restrict__ rowptr, const int* __restrict__ srcs,
        const float* __restrict__ a_s, const float* __restrict__ a_d,
        const u8* __restrict__ xs, const f16* __restrict__ skip2,
        float* __restrict__ out, int n) {
    __shared__ f16 alpha_lds[4][4 * ALDS_STRIDE];
    const int wid = threadIdx.x >> 6, lane = threadIdx.x & 63;
    const int d = blockIdx.x * 4 + wid;
    if (d >= n) return;
    const int base = rowptr[d];
    const int deg  = rowptr[d + 1] - base;
    float4 acc = {0.f, 0.f, 0.f, 0.f};
    if (deg > 0)
        acc = gat_node_acc(srcs, a_s, xs, alpha_lds[wid],
                           a_d + (size_t)d * 4, base, deg, lane);
    f16x4 sk = *reinterpret_cast<const f16x4*>(skip2 + (size_t)d * D1 + lane * 4);
    float4 ov;
    ov.x = acc.x + (float)sk[0];
    ov.y = acc.y + (float)sk[1];
    ov.z = acc.z + (float)sk[2];
    ov.w = acc.w + (float)sk[3];
    *reinterpret_cast<float4*>(out + (size_t)d * D1 + lane * 4) = ov;
}

extern "C" void kernel_launch(void* const* d_in, const int* in_sizes, int n_in,
                              void* d_out, int out_size, void* d_ws, size_t ws_size,
                              hipStream_t stream) {
    const float* x     = (const float*)d_in[0];
    const int*   ei    = (const int*)d_in[1];
    const float* Wsrc1 = (const float*)d_in[2];
    const float* Wdst1 = (const float*)d_in[3];
    const float* atts1 = (const float*)d_in[4];
    const float* attd1 = (const float*)d_in[5];
    const float* b1    = (const float*)d_in[6];
    const float* Wlin1 = (const float*)d_in[7];
    const float* blin1 = (const float*)d_in[8];
    const float* gamma = (const float*)d_in[9];
    const float* beta  = (const float*)d_in[10];
    const float* Wsrc2 = (const float*)d_in[11];
    const float* Wdst2 = (const float*)d_in[12];
    const float* atts2 = (const float*)d_in[13];
    const float* attd2 = (const float*)d_in[14];
    const float* b2    = (const float*)d_in[15];
    const float* Wlin2 = (const float*)d_in[16];
    const float* blin2 = (const float*)d_in[17];

    const int n  = in_sizes[0] / DIN;   // 50000
    const int ne = in_sizes[1] / 2;     // 800000
    const int* src = ei;
    const int* dst = ei + ne;

    char* w8 = (char*)d_ws;
    size_t off = 0;
    auto alloc = [&](size_t bytes) -> void* {
        void* p = w8 + off;
        off += (bytes + 255) & ~(size_t)255;
        return p;
    };
    f16*  h16    = (f16*)alloc((size_t)n * D1 * 2);
    f16*  x16    = h16;   // union: x16 dead before gather_ln writes h16
    u8*   xs8    = (u8*)alloc((size_t)n * D1);
    f16*  skip1  = (f16*)alloc((size_t)n * D1 * 2);   // reused as skip2
    float* a_s1  = (float*)alloc((size_t)n * HH * 4);
    float* a_d1  = (float*)alloc((size_t)n * HH * 4);
    float* a_s2  = (float*)alloc((size_t)n * HH * 4);
    float* a_d2  = (float*)alloc((size_t)n * HH * 4);
    float* Vs1   = (float*)alloc((size_t)D1 * HH * 4);
    float* Vd1   = (float*)alloc((size_t)D1 * HH * 4);
    float* Vs2   = (float*)alloc((size_t)D1 * HH * 4);
    float* Vd2   = (float*)alloc((size_t)D1 * HH * 4);
    int* rowptr   = (int*)alloc(((size_t)n + 1) * 4);
    int* degbuf   = (int*)alloc((size_t)n * 4);
    int* degcur   = (int*)alloc((size_t)n * 4);
    int* partial  = (int*)alloc((size_t)n * 4);
    int* blocksum = (int*)alloc(1024 * 4);
    int* srcs_csr = (int*)alloc((size_t)ne * 4);
    f16* WpS1  = (f16*)alloc((size_t)DIN * D1 * 2);
    f16* WpL1  = (f16*)alloc((size_t)DIN * D1 * 2);
    f16* WpS2  = (f16*)alloc((size_t)D1 * D1 * 2);
    f16* WpL2  = (f16*)alloc((size_t)D1 * D1 * 2);

    float* out = (float*)d_out;

    const int nb_node4  = (n + 3) / 4;
    const int nb_node64 = (n + 63) / 64;
    const int nb_e      = (ne + 255) / 256;
    const int nb_gemm   = (n + 63) / 64;
    const int nb_scan   = (n + 1023) / 1024;
    const int nb_pack   = (DIN * D1 + D1 * D1 + 255) / 256;
    const int nb_v      = 2 * (DIN + D1);

    // prep: W pack + make_v + deg (independent pieces, one launch)
    (void)hipMemsetAsync(degbuf, 0, (size_t)n * 4, stream);
    prep_deg_kernel<<<nb_pack + nb_v + nb_e, 256, 0, stream>>>(
        Wsrc1, Wlin1, Wsrc2, Wlin2, Wdst1, Wdst2,
        atts1, attd1, atts2, attd2,
        WpS1, WpL1, WpS2, WpL2, Vs1, Vd1, Vs2, Vd2,
        dst, degbuf, ne, nb_pack, nb_v);
    // cvt+scores (needs Vs1/Vd1) fused with scan1 (needs degbuf)
    cvt_scores_scan1_kernel<<<nb_node64 + nb_scan, 1024, 0, stream>>>(
        x, Vs1, Vd1, x16, a_s1, a_d1, n, degbuf, partial, blocksum, nb_node64);
    scan_phase3<<<nb_scan, 1024, 0, stream>>>(partial, blocksum, degbuf, rowptr, degcur, n);
    fill_kernel<<<nb_e, 256, 0, stream>>>(src, dst, degcur, srcs_csr, ne);
    gemm_dual_mfma<DIN><<<nb_gemm, 256, 0, stream>>>(x16, WpS1, WpL1, b1, blin1, xs8, skip1, n);
    gat_gather_ln_kernel<<<nb_node4, 256, 0, stream>>>(rowptr, srcs_csr, a_s1, a_d1, xs8,
                                                       skip1, gamma, beta, Vs2, Vd2,
                                                       h16, a_s2, a_d2, n);
    gemm_dual_mfma<D1><<<nb_gemm, 256, 0, stream>>>(h16, WpS2, WpL2, b2, blin2, xs8, skip1, n);
    gat_gather_out_kernel<<<nb_node4, 256, 0, stream>>>(rowptr, srcs_csr, a_s2, a_d2,
                                                        xs8, skip1, out, n);
}